// Round 1
// baseline (208.740 us; speedup 1.0000x reference)
//
#include <hip/hip_runtime.h>
#include <math.h>

#define EPS 1e-8f
#define LAMBDA 1e-3f

// 4x4 pose matmul: v (4x4) = x (4x4) * w (4x4), row-major flattened to 16.
__device__ __forceinline__ void mat4x4(float4 xv0, float4 xv1, float4 xv2, float4 xv3,
                                       float4 w0, float4 w1, float4 w2, float4 w3,
                                       float* __restrict__ v) {
  {
    float x0 = xv0.x, x1 = xv0.y, x2 = xv0.z, x3 = xv0.w;
    v[0] = fmaf(x3, w3.x, fmaf(x2, w2.x, fmaf(x1, w1.x, x0 * w0.x)));
    v[1] = fmaf(x3, w3.y, fmaf(x2, w2.y, fmaf(x1, w1.y, x0 * w0.y)));
    v[2] = fmaf(x3, w3.z, fmaf(x2, w2.z, fmaf(x1, w1.z, x0 * w0.z)));
    v[3] = fmaf(x3, w3.w, fmaf(x2, w2.w, fmaf(x1, w1.w, x0 * w0.w)));
  }
  {
    float x0 = xv1.x, x1 = xv1.y, x2 = xv1.z, x3 = xv1.w;
    v[4] = fmaf(x3, w3.x, fmaf(x2, w2.x, fmaf(x1, w1.x, x0 * w0.x)));
    v[5] = fmaf(x3, w3.y, fmaf(x2, w2.y, fmaf(x1, w1.y, x0 * w0.y)));
    v[6] = fmaf(x3, w3.z, fmaf(x2, w2.z, fmaf(x1, w1.z, x0 * w0.z)));
    v[7] = fmaf(x3, w3.w, fmaf(x2, w2.w, fmaf(x1, w1.w, x0 * w0.w)));
  }
  {
    float x0 = xv2.x, x1 = xv2.y, x2 = xv2.z, x3 = xv2.w;
    v[8]  = fmaf(x3, w3.x, fmaf(x2, w2.x, fmaf(x1, w1.x, x0 * w0.x)));
    v[9]  = fmaf(x3, w3.y, fmaf(x2, w2.y, fmaf(x1, w1.y, x0 * w0.y)));
    v[10] = fmaf(x3, w3.z, fmaf(x2, w2.z, fmaf(x1, w1.z, x0 * w0.z)));
    v[11] = fmaf(x3, w3.w, fmaf(x2, w2.w, fmaf(x1, w1.w, x0 * w0.w)));
  }
  {
    float x0 = xv3.x, x1 = xv3.y, x2 = xv3.z, x3 = xv3.w;
    v[12] = fmaf(x3, w3.x, fmaf(x2, w2.x, fmaf(x1, w1.x, x0 * w0.x)));
    v[13] = fmaf(x3, w3.y, fmaf(x2, w2.y, fmaf(x1, w1.y, x0 * w0.y)));
    v[14] = fmaf(x3, w3.z, fmaf(x2, w2.z, fmaf(x1, w1.z, x0 * w0.z)));
    v[15] = fmaf(x3, w3.w, fmaf(x2, w2.w, fmaf(x1, w1.w, x0 * w0.w)));
  }
}

// One block per output row n (508 rows). 512 threads = 16 chunks x 32 c.
// Thread (chunk,c) owns output capsule c for B in [chunk*18, chunk*18+18).
// B-loop unrolled by 2: both iterations' loads issued up front, softmax
// butterfly reductions for the pair run as two interleaved chains so the
// ds_swizzle latency is paid once per pair instead of once per iteration.
__launch_bounds__(512, 4)
__global__ void convcaps_kernel(const float* __restrict__ x,
                                const float* __restrict__ wgl,
                                const float* __restrict__ beta_u,
                                const float* __restrict__ beta_a,
                                float* __restrict__ out) {
  __shared__ float xr[288][16];       // pose patches, 18 KB
  __shared__ float a_sh[288];         // a/(a+EPS)
  __shared__ float red[33][256];      // per-wave partials (A1[16],A2[16],S)
  __shared__ float mu_l[32][17];      // +1 pad: stride 17 coprime 32
  __shared__ float i2s_l[32][17];     // 1/(2*sigma)
  __shared__ float hl_l[32][17];      // 0.5*ln(sigma)
  __shared__ float S_l[32];
  __shared__ float aout_l[32];
  __shared__ float lnao_l[32];

  const int tid = threadIdx.x;
  const int n = blockIdx.x;
  const int c = tid & 31;
  const int chunk = tid >> 5;         // 0..15

  // ---- stage 9 source rows (float4): xr[B][s], a_sh[B] ----
  for (int idx = tid; idx < 1224; idx += 512) {   // 9 * 136 float4
    int t = idx / 136;
    int e4 = idx - t * 136;
    int g = 9 * n + t;
    int bg = g / 2286;                 // 2286 = 9*254
    int ki = (g % 2286) / 762;         // 762 = 3*254
    int owp = g % 254;
    const float4* src = reinterpret_cast<const float4*>(x) +
                        (size_t)((bg * 256 + ki + owp) * 4) * 136;
    float4 val = src[e4];
    if (e4 < 128) reinterpret_cast<float4*>(&xr[0][0])[t * 128 + e4] = val;
    else          reinterpret_cast<float4*>(a_sh)[t * 8 + (e4 - 128)] = val;
  }
  __syncthreads();
  for (int e = tid; e < 288; e += 512) { float a = a_sh[e]; a_sh[e] = a / (a + EPS); }
  __syncthreads();

  float A1[16], A2[16], Ssum;
  float mu[16], i2s[16];
  const size_t rbase = 276352;         // 2*254*544
  float* rout = out + rbase + ((size_t)n * 288) * 32 + c;

  for (int pass = 0; pass < 3; ++pass) {
    #pragma unroll
    for (int s = 0; s < 16; ++s) { A1[s] = 0.f; A2[s] = 0.f; }
    Ssum = 0.f;
    float bias = 0.f;
    if (pass > 0) {
      float Hl = 0.f;
      #pragma unroll
      for (int s = 0; s < 16; ++s) {
        mu[s] = mu_l[c][s];
        i2s[s] = i2s_l[c][s];
        Hl += hl_l[c][s];
      }
      bias = lnao_l[c] - Hl;
    }

    for (int p = 0; p < 9; ++p) {
      const int Ba = chunk * 18 + 2 * p;
      // issue both iterations' loads up front (global w ~200cy, LDS x ~60cy)
      const float4* wpa = reinterpret_cast<const float4*>(wgl) + ((size_t)(Ba * 32 + c)) * 4;
      const float4* wpb = wpa + 128;   // +32*16 floats = next B
      float4 wa0 = wpa[0], wa1 = wpa[1], wa2 = wpa[2], wa3 = wpa[3];
      float4 wb0 = wpb[0], wb1 = wpb[1], wb2 = wpb[2], wb3 = wpb[3];
      const float4* xp = reinterpret_cast<const float4*>(&xr[Ba][0]);
      float4 xa0 = xp[0], xa1 = xp[1], xa2 = xp[2], xa3 = xp[3];
      float4 xb0 = xp[4], xb1 = xp[5], xb2 = xp[6], xb3 = xp[7];

      float va[16], vb[16];
      mat4x4(xa0, xa1, xa2, xa3, wa0, wa1, wa2, wa3, va);
      mat4x4(xb0, xb1, xb2, xb3, wb0, wb1, wb2, wb3, vb);

      float afa = a_sh[Ba];
      float afb = a_sh[Ba + 1];
      float wgta, wgtb;
      if (pass == 0) {
        wgta = afa * 0.03125f;
        wgtb = afb * 0.03125f;
      } else {
        // 4-way partial trees: chain depth 4+2 instead of 16
        float qa0 = 0.f, qa1 = 0.f, qa2 = 0.f, qa3 = 0.f;
        float qb0 = 0.f, qb1 = 0.f, qb2 = 0.f, qb3 = 0.f;
        #pragma unroll
        for (int s = 0; s < 16; s += 4) {
          float da0 = va[s]     - mu[s];     qa0 = fmaf(da0 * da0, i2s[s],     qa0);
          float da1 = va[s + 1] - mu[s + 1]; qa1 = fmaf(da1 * da1, i2s[s + 1], qa1);
          float da2 = va[s + 2] - mu[s + 2]; qa2 = fmaf(da2 * da2, i2s[s + 2], qa2);
          float da3 = va[s + 3] - mu[s + 3]; qa3 = fmaf(da3 * da3, i2s[s + 3], qa3);
          float db0 = vb[s]     - mu[s];     qb0 = fmaf(db0 * db0, i2s[s],     qb0);
          float db1 = vb[s + 1] - mu[s + 1]; qb1 = fmaf(db1 * db1, i2s[s + 1], qb1);
          float db2 = vb[s + 2] - mu[s + 2]; qb2 = fmaf(db2 * db2, i2s[s + 2], qb2);
          float db3 = vb[s + 3] - mu[s + 3]; qb3 = fmaf(db3 * db3, i2s[s + 3], qb3);
        }
        float lna = bias - ((qa0 + qa1) + (qa2 + qa3));
        float lnb = bias - ((qb0 + qb1) + (qb2 + qb3));

        // dual interleaved butterflies: two independent chains, latency paid once
        float mxa = lna, mxb = lnb;
        #pragma unroll
        for (int off = 16; off >= 1; off >>= 1) {
          float ta = __shfl_xor(mxa, off, 32);
          float tb = __shfl_xor(mxb, off, 32);
          mxa = fmaxf(mxa, ta);
          mxb = fmaxf(mxb, tb);
        }
        float ea = __expf(lna - mxa);
        float eb = __expf(lnb - mxb);
        float sa = ea, sb = eb;
        #pragma unroll
        for (int off = 16; off >= 1; off >>= 1) {
          float ta = __shfl_xor(sa, off, 32);
          float tb = __shfl_xor(sb, off, 32);
          sa += ta;
          sb += tb;
        }
        float r2a = ea * __builtin_amdgcn_rcpf(sa);
        float r2b = eb * __builtin_amdgcn_rcpf(sb);
        if (pass == 2) {
          rout[(size_t)Ba * 32] = r2a;
          rout[(size_t)(Ba + 1) * 32] = r2b;
        }
        wgta = r2a * afa;
        wgtb = r2b * afb;
      }
      #pragma unroll
      for (int s = 0; s < 16; ++s) {
        float pa = wgta * va[s];
        float pb = wgtb * vb[s];
        A1[s] += pa + pb;
        A2[s] = fmaf(pb, vb[s], fmaf(pa, va[s], A2[s]));
      }
      Ssum += wgta + wgtb;
    }

    // ---- pre-reduce across the two wave halves, then LDS across 8 waves ----
    #pragma unroll
    for (int s = 0; s < 16; ++s) {
      A1[s] += __shfl_xor(A1[s], 32, 64);
      A2[s] += __shfl_xor(A2[s], 32, 64);
    }
    Ssum += __shfl_xor(Ssum, 32, 64);
    if ((tid & 63) < 32) {
      int col = (tid >> 6) * 32 + c;
      #pragma unroll
      for (int s = 0; s < 16; ++s) { red[s][col] = A1[s]; red[16 + s][col] = A2[s]; }
      red[32][col] = Ssum;
    }
    __syncthreads();

    // finalize mu/sigma: exactly one (c2,s) task per thread
    {
      int s = tid >> 5;
      int c2 = tid & 31;
      float a1 = 0.f, a2 = 0.f, ss = 0.f;
      #pragma unroll
      for (int ch = 0; ch < 8; ++ch) {
        int col = ch * 32 + c2;
        a1 += red[s][col];
        a2 += red[16 + s][col];
        ss += red[32][col];
      }
      float inv = __builtin_amdgcn_rcpf(ss + EPS);
      float m = a1 * inv;
      float Sc = ss * inv;
      float sg = fmaf(-m * m, 2.0f - Sc, a2 * inv) + EPS;   // sigma_sq
      mu_l[c2][s] = m;
      i2s_l[c2][s] = 0.5f * __builtin_amdgcn_rcpf(sg);
      hl_l[c2][s] = 0.5f * __logf(sg);
      if (s == 0) S_l[c2] = ss;
    }
    __syncthreads();

    if (tid < 32) {
      float sh = 0.f;
      #pragma unroll
      for (int s = 0; s < 16; ++s) sh += hl_l[tid][s];
      float cost = fmaf(beta_u[tid], 16.0f, sh) * S_l[tid];
      float z = LAMBDA * (beta_a[tid] - cost);
      float ao = __builtin_amdgcn_rcpf(1.0f + __expf(-z));
      aout_l[tid] = ao;
      lnao_l[tid] = __logf(ao);
    }
    __syncthreads();
  }

  // ---- outputs: row n = [mu (512) | a_out (32)], coalesced ----
  {
    int c2 = tid >> 4;
    int s = tid & 15;
    out[(size_t)n * 544 + tid] = mu_l[c2][s];
  }
  if (tid < 32) out[(size_t)n * 544 + 512 + tid] = aout_l[tid];
}

extern "C" void kernel_launch(void* const* d_in, const int* in_sizes, int n_in,
                              void* d_out, int out_size, void* d_ws, size_t ws_size,
                              hipStream_t stream) {
  const float* x  = (const float*)d_in[0];
  const float* w  = (const float*)d_in[1];
  const float* bu = (const float*)d_in[2];
  const float* ba = (const float*)d_in[3];
  float* out = (float*)d_out;
  convcaps_kernel<<<dim3(508), dim3(512), 0, stream>>>(x, w, bu, ba, out);
}

// Round 2
// 160.179 us; speedup vs baseline: 1.3032x; 1.3032x over previous
//
#include <hip/hip_runtime.h>
#include <math.h>

#define EPS 1e-8f
#define LAMBDA 1e-3f

// DPP lane-permute: executes in the VALU pipe (no LDS round trip, no addr calc).
template <int CTRL>
__device__ __forceinline__ float dppmov(float v) {
  return __int_as_float(__builtin_amdgcn_update_dpp(
      0, __float_as_int(v), CTRL, 0xF, 0xF, true));
}
// lane l -> lane l^16 within each 32-lane half (BitMode: xor=16, and=0x1F)
__device__ __forceinline__ float swz_xor16(float v) {
  return __int_as_float(__builtin_amdgcn_ds_swizzle(__float_as_int(v), 0x401F));
}

// 32-lane reduce via DPP: xor1(quad_perm), xor2(quad_perm), xor7(row_half_mirror),
// xor15(row_mirror) span lanes 0..15 pairs; one ds_swizzle covers the xor16 step.
// Span argument: after {1,2} every lane holds its quad; ^7 merges the two quads of
// an 8-group; ^15 merges the two 8-groups of a 16-row; ^16 merges the two rows.
__device__ __forceinline__ float redsum32(float v) {
  v += dppmov<0xB1>(v);    // quad_perm [1,0,3,2] == xor 1
  v += dppmov<0x4E>(v);    // quad_perm [2,3,0,1] == xor 2
  v += dppmov<0x141>(v);   // row_half_mirror    == xor 7
  v += dppmov<0x140>(v);   // row_mirror         == xor 15
  v += swz_xor16(v);       // xor 16
  return v;
}
__device__ __forceinline__ float redmax32(float v) {
  v = fmaxf(v, dppmov<0xB1>(v));
  v = fmaxf(v, dppmov<0x4E>(v));
  v = fmaxf(v, dppmov<0x141>(v));
  v = fmaxf(v, dppmov<0x140>(v));
  v = fmaxf(v, swz_xor16(v));
  return v;
}

// One block per output row n (508 rows). 512 threads = 16 chunks x 32 c.
// Thread (chunk,c) owns output capsule c for B in [chunk*18, chunk*18+18).
// su = sum_c(r*a) == a exactly (softmax sums to 1), so the c-normalization
// is folded into af = a/(a+EPS) at staging -> one fewer shuffle tree.
// NOTE: allocator holds at 64 VGPR here; keep live state small (round-1's
// unroll-by-2 spilled ~156 MB of scratch writes).
__launch_bounds__(512, 4)
__global__ void convcaps_kernel(const float* __restrict__ x,
                                const float* __restrict__ wgl,
                                const float* __restrict__ beta_u,
                                const float* __restrict__ beta_a,
                                float* __restrict__ out) {
  __shared__ float xr[288][16];       // pose patches, 18 KB
  __shared__ float a_sh[288];         // a/(a+EPS)
  __shared__ float red[33][256];      // per-wave partials (A1[16],A2[16],S)
  __shared__ float mu_l[32][17];      // +1 pad: stride 17 coprime 32
  __shared__ float i2s_l[32][17];     // 1/(2*sigma)
  __shared__ float hl_l[32][17];      // 0.5*ln(sigma)
  __shared__ float S_l[32];
  __shared__ float aout_l[32];
  __shared__ float lnao_l[32];

  const int tid = threadIdx.x;
  const int n = blockIdx.x;
  const int c = tid & 31;
  const int chunk = tid >> 5;         // 0..15

  // ---- stage 9 source rows (float4): xr[B][s], a_sh[B] ----
  for (int idx = tid; idx < 1224; idx += 512) {   // 9 * 136 float4
    int t = idx / 136;
    int e4 = idx - t * 136;
    int g = 9 * n + t;
    int bg = g / 2286;                 // 2286 = 9*254
    int ki = (g % 2286) / 762;         // 762 = 3*254
    int owp = g % 254;
    const float4* src = reinterpret_cast<const float4*>(x) +
                        (size_t)((bg * 256 + ki + owp) * 4) * 136;
    float4 val = src[e4];
    if (e4 < 128) reinterpret_cast<float4*>(&xr[0][0])[t * 128 + e4] = val;
    else          reinterpret_cast<float4*>(a_sh)[t * 8 + (e4 - 128)] = val;
  }
  __syncthreads();
  for (int e = tid; e < 288; e += 512) { float a = a_sh[e]; a_sh[e] = a / (a + EPS); }
  __syncthreads();

  float A1[16], A2[16], Ssum;
  float mu[16], i2s[16];
  const size_t rbase = 276352;         // 2*254*544

  for (int pass = 0; pass < 3; ++pass) {
    #pragma unroll
    for (int s = 0; s < 16; ++s) { A1[s] = 0.f; A2[s] = 0.f; }
    Ssum = 0.f;
    float bias = 0.f;
    if (pass > 0) {
      float Hl = 0.f;
      #pragma unroll
      for (int s = 0; s < 16; ++s) {
        mu[s] = mu_l[c][s];
        i2s[s] = i2s_l[c][s];
        Hl += hl_l[c][s];
      }
      bias = lnao_l[c] - Hl;
    }

    for (int i = 0; i < 18; ++i) {
      int B = chunk * 18 + i;
      const float4* wp = reinterpret_cast<const float4*>(wgl + ((size_t)(B * 32 + c)) * 16);
      float4 w0 = wp[0], w1 = wp[1], w2 = wp[2], w3 = wp[3];
      const float4* xp = reinterpret_cast<const float4*>(&xr[B][0]);
      float4 xv0 = xp[0], xv1 = xp[1], xv2 = xp[2], xv3 = xp[3];
      float v[16];
      {
        float x0 = xv0.x, x1 = xv0.y, x2 = xv0.z, x3 = xv0.w;
        v[0] = fmaf(x3, w3.x, fmaf(x2, w2.x, fmaf(x1, w1.x, x0 * w0.x)));
        v[1] = fmaf(x3, w3.y, fmaf(x2, w2.y, fmaf(x1, w1.y, x0 * w0.y)));
        v[2] = fmaf(x3, w3.z, fmaf(x2, w2.z, fmaf(x1, w1.z, x0 * w0.z)));
        v[3] = fmaf(x3, w3.w, fmaf(x2, w2.w, fmaf(x1, w1.w, x0 * w0.w)));
      }
      {
        float x0 = xv1.x, x1 = xv1.y, x2 = xv1.z, x3 = xv1.w;
        v[4] = fmaf(x3, w3.x, fmaf(x2, w2.x, fmaf(x1, w1.x, x0 * w0.x)));
        v[5] = fmaf(x3, w3.y, fmaf(x2, w2.y, fmaf(x1, w1.y, x0 * w0.y)));
        v[6] = fmaf(x3, w3.z, fmaf(x2, w2.z, fmaf(x1, w1.z, x0 * w0.z)));
        v[7] = fmaf(x3, w3.w, fmaf(x2, w2.w, fmaf(x1, w1.w, x0 * w0.w)));
      }
      {
        float x0 = xv2.x, x1 = xv2.y, x2 = xv2.z, x3 = xv2.w;
        v[8]  = fmaf(x3, w3.x, fmaf(x2, w2.x, fmaf(x1, w1.x, x0 * w0.x)));
        v[9]  = fmaf(x3, w3.y, fmaf(x2, w2.y, fmaf(x1, w1.y, x0 * w0.y)));
        v[10] = fmaf(x3, w3.z, fmaf(x2, w2.z, fmaf(x1, w1.z, x0 * w0.z)));
        v[11] = fmaf(x3, w3.w, fmaf(x2, w2.w, fmaf(x1, w1.w, x0 * w0.w)));
      }
      {
        float x0 = xv3.x, x1 = xv3.y, x2 = xv3.z, x3 = xv3.w;
        v[12] = fmaf(x3, w3.x, fmaf(x2, w2.x, fmaf(x1, w1.x, x0 * w0.x)));
        v[13] = fmaf(x3, w3.y, fmaf(x2, w2.y, fmaf(x1, w1.y, x0 * w0.y)));
        v[14] = fmaf(x3, w3.z, fmaf(x2, w2.z, fmaf(x1, w1.z, x0 * w0.z)));
        v[15] = fmaf(x3, w3.w, fmaf(x2, w2.w, fmaf(x1, w1.w, x0 * w0.w)));
      }

      float af = a_sh[B];
      float wgt;
      if (pass == 0) {
        wgt = af * 0.03125f;
      } else {
        // 4-way partial trees: chain depth 4+2 instead of 16 (register-neutral)
        float q0 = 0.f, q1 = 0.f, q2 = 0.f, q3 = 0.f;
        #pragma unroll
        for (int s = 0; s < 16; s += 4) {
          float d0 = v[s]     - mu[s];     q0 = fmaf(d0 * d0, i2s[s],     q0);
          float d1 = v[s + 1] - mu[s + 1]; q1 = fmaf(d1 * d1, i2s[s + 1], q1);
          float d2 = v[s + 2] - mu[s + 2]; q2 = fmaf(d2 * d2, i2s[s + 2], q2);
          float d3 = v[s + 3] - mu[s + 3]; q3 = fmaf(d3 * d3, i2s[s + 3], q3);
        }
        float lnap = bias - ((q0 + q1) + (q2 + q3));
        float mx = redmax32(lnap);
        float e = __expf(lnap - mx);
        float se = redsum32(e);
        float r2 = e * __builtin_amdgcn_rcpf(se);
        if (pass == 2) out[rbase + ((size_t)n * 288 + B) * 32 + c] = r2;
        wgt = r2 * af;
      }
      #pragma unroll
      for (int s = 0; s < 16; ++s) {
        float p = wgt * v[s];
        A1[s] += p;
        A2[s] = fmaf(p, v[s], A2[s]);
      }
      Ssum += wgt;
    }

    // ---- pre-reduce across the two wave halves, then LDS across 8 waves ----
    #pragma unroll
    for (int s = 0; s < 16; ++s) {
      A1[s] += __shfl_xor(A1[s], 32, 64);
      A2[s] += __shfl_xor(A2[s], 32, 64);
    }
    Ssum += __shfl_xor(Ssum, 32, 64);
    if ((tid & 63) < 32) {
      int col = (tid >> 6) * 32 + c;
      #pragma unroll
      for (int s = 0; s < 16; ++s) { red[s][col] = A1[s]; red[16 + s][col] = A2[s]; }
      red[32][col] = Ssum;
    }
    __syncthreads();

    // finalize mu/sigma: exactly one (c2,s) task per thread
    {
      int s = tid >> 5;
      int c2 = tid & 31;
      float a1 = 0.f, a2 = 0.f, ss = 0.f;
      #pragma unroll
      for (int ch = 0; ch < 8; ++ch) {
        int col = ch * 32 + c2;
        a1 += red[s][col];
        a2 += red[16 + s][col];
        ss += red[32][col];
      }
      float inv = __builtin_amdgcn_rcpf(ss + EPS);
      float m = a1 * inv;
      float Sc = ss * inv;
      float sg = fmaf(-m * m, 2.0f - Sc, a2 * inv) + EPS;   // sigma_sq
      mu_l[c2][s] = m;
      i2s_l[c2][s] = 0.5f * __builtin_amdgcn_rcpf(sg);
      hl_l[c2][s] = 0.5f * __logf(sg);
      if (s == 0) S_l[c2] = ss;
    }
    __syncthreads();

    if (tid < 32) {
      float sh = 0.f;
      #pragma unroll
      for (int s = 0; s < 16; ++s) sh += hl_l[tid][s];
      float cost = fmaf(beta_u[tid], 16.0f, sh) * S_l[tid];
      float z = LAMBDA * (beta_a[tid] - cost);
      float ao = __builtin_amdgcn_rcpf(1.0f + __expf(-z));
      aout_l[tid] = ao;
      lnao_l[tid] = __logf(ao);
    }
    __syncthreads();
  }

  // ---- outputs: row n = [mu (512) | a_out (32)], coalesced ----
  {
    int c2 = tid >> 4;
    int s = tid & 15;
    out[(size_t)n * 544 + tid] = mu_l[c2][s];
  }
  if (tid < 32) out[(size_t)n * 544 + 512 + tid] = aout_l[tid];
}

extern "C" void kernel_launch(void* const* d_in, const int* in_sizes, int n_in,
                              void* d_out, int out_size, void* d_ws, size_t ws_size,
                              hipStream_t stream) {
  const float* x  = (const float*)d_in[0];
  const float* w  = (const float*)d_in[1];
  const float* bu = (const float*)d_in[2];
  const float* ba = (const float*)d_in[3];
  float* out = (float*)d_out;
  convcaps_kernel<<<dim3(508), dim3(512), 0, stream>>>(x, w, bu, ba, out);
}

// Round 3
// 148.064 us; speedup vs baseline: 1.4098x; 1.0818x over previous
//
#include <hip/hip_runtime.h>
#include <math.h>

#define EPS 1e-8f
#define LAMBDA 1e-3f

// DPP lane-permute: executes in the VALU pipe (no LDS round trip, no addr calc).
template <int CTRL>
__device__ __forceinline__ float dppmov(float v) {
  return __int_as_float(__builtin_amdgcn_update_dpp(
      0, __float_as_int(v), CTRL, 0xF, 0xF, true));
}
// lane l -> lane l^16 within each 32-lane half (BitMode: xor=16, and=0x1F)
__device__ __forceinline__ float swz_xor16(float v) {
  return __int_as_float(__builtin_amdgcn_ds_swizzle(__float_as_int(v), 0x401F));
}

// 32-lane reduce via DPP: xor1(quad_perm), xor2(quad_perm), xor7(row_half_mirror),
// xor15(row_mirror) span lanes 0..15 pairs; one ds_swizzle covers the xor16 step.
__device__ __forceinline__ float redsum32(float v) {
  v += dppmov<0xB1>(v);    // quad_perm [1,0,3,2] == xor 1
  v += dppmov<0x4E>(v);    // quad_perm [2,3,0,1] == xor 2
  v += dppmov<0x141>(v);   // row_half_mirror    == xor 7
  v += dppmov<0x140>(v);   // row_mirror         == xor 15
  v += swz_xor16(v);       // xor 16
  return v;
}
__device__ __forceinline__ float redmax32(float v) {
  v = fmaxf(v, dppmov<0xB1>(v));
  v = fmaxf(v, dppmov<0x4E>(v));
  v = fmaxf(v, dppmov<0x141>(v));
  v = fmaxf(v, dppmov<0x140>(v));
  v = fmaxf(v, swz_xor16(v));
  return v;
}

// One block per output row n (508 rows). 512 threads = 16 chunks x 32 c.
// Thread (chunk,c) owns output capsule c for B in [chunk*18, chunk*18+18).
// su = sum_c(r*a) == a exactly (softmax sums to 1), so the c-normalization
// is folded into af = a/(a+EPS) at staging -> one fewer shuffle tree.
//
// launch_bounds(512, 2): the (512,4) bound forced an effective 64-VGPR cap
// (8 waves/SIMD reservation) and anything past 64 regs SPILLED (round-1/2:
// WRITE_SIZE 36.6 -> 133/193 MB at constant VGPR_Count=64). Occupancy is
// LDS-capped (59 KB -> 2 blocks/CU) and grid-capped (508 blocks) at 4
// waves/SIMD regardless, so allowing ~128 VGPRs costs zero occupancy.
__launch_bounds__(512, 2)
__global__ void convcaps_kernel(const float* __restrict__ x,
                                const float* __restrict__ wgl,
                                const float* __restrict__ beta_u,
                                const float* __restrict__ beta_a,
                                float* __restrict__ out) {
  __shared__ float xr[288][16];       // pose patches, 18 KB
  __shared__ float a_sh[288];         // a/(a+EPS)
  __shared__ float red[33][256];      // per-wave partials (A1[16],A2[16],S)
  __shared__ float mu_l[32][17];      // +1 pad: stride 17 coprime 32
  __shared__ float i2s_l[32][17];     // 1/(2*sigma)
  __shared__ float hl_l[32][17];      // 0.5*ln(sigma)
  __shared__ float S_l[32];
  __shared__ float aout_l[32];
  __shared__ float lnao_l[32];

  const int tid = threadIdx.x;
  const int n = blockIdx.x;
  const int c = tid & 31;
  const int chunk = tid >> 5;         // 0..15

  // ---- stage 9 source rows (float4): xr[B][s], a_sh[B] ----
  for (int idx = tid; idx < 1224; idx += 512) {   // 9 * 136 float4
    int t = idx / 136;
    int e4 = idx - t * 136;
    int g = 9 * n + t;
    int bg = g / 2286;                 // 2286 = 9*254
    int ki = (g % 2286) / 762;         // 762 = 3*254
    int owp = g % 254;
    const float4* src = reinterpret_cast<const float4*>(x) +
                        (size_t)((bg * 256 + ki + owp) * 4) * 136;
    float4 val = src[e4];
    if (e4 < 128) reinterpret_cast<float4*>(&xr[0][0])[t * 128 + e4] = val;
    else          reinterpret_cast<float4*>(a_sh)[t * 8 + (e4 - 128)] = val;
  }
  __syncthreads();
  for (int e = tid; e < 288; e += 512) { float a = a_sh[e]; a_sh[e] = a / (a + EPS); }
  __syncthreads();

  float A1[16], A2[16], Ssum;
  float mu[16], i2s[16];
  const size_t rbase = 276352;         // 2*254*544

  for (int pass = 0; pass < 3; ++pass) {
    #pragma unroll
    for (int s = 0; s < 16; ++s) { A1[s] = 0.f; A2[s] = 0.f; }
    Ssum = 0.f;
    float bias = 0.f;
    if (pass > 0) {
      float Hl = 0.f;
      #pragma unroll
      for (int s = 0; s < 16; ++s) {
        mu[s] = mu_l[c][s];
        i2s[s] = i2s_l[c][s];
        Hl += hl_l[c][s];
      }
      bias = lnao_l[c] - Hl;
    }

    for (int i = 0; i < 18; ++i) {
      int B = chunk * 18 + i;
      const float4* wp = reinterpret_cast<const float4*>(wgl + ((size_t)(B * 32 + c)) * 16);
      float4 w0 = wp[0], w1 = wp[1], w2 = wp[2], w3 = wp[3];
      const float4* xp = reinterpret_cast<const float4*>(&xr[B][0]);
      float4 xv0 = xp[0], xv1 = xp[1], xv2 = xp[2], xv3 = xp[3];
      float v[16];
      {
        float x0 = xv0.x, x1 = xv0.y, x2 = xv0.z, x3 = xv0.w;
        v[0] = fmaf(x3, w3.x, fmaf(x2, w2.x, fmaf(x1, w1.x, x0 * w0.x)));
        v[1] = fmaf(x3, w3.y, fmaf(x2, w2.y, fmaf(x1, w1.y, x0 * w0.y)));
        v[2] = fmaf(x3, w3.z, fmaf(x2, w2.z, fmaf(x1, w1.z, x0 * w0.z)));
        v[3] = fmaf(x3, w3.w, fmaf(x2, w2.w, fmaf(x1, w1.w, x0 * w0.w)));
      }
      {
        float x0 = xv1.x, x1 = xv1.y, x2 = xv1.z, x3 = xv1.w;
        v[4] = fmaf(x3, w3.x, fmaf(x2, w2.x, fmaf(x1, w1.x, x0 * w0.x)));
        v[5] = fmaf(x3, w3.y, fmaf(x2, w2.y, fmaf(x1, w1.y, x0 * w0.y)));
        v[6] = fmaf(x3, w3.z, fmaf(x2, w2.z, fmaf(x1, w1.z, x0 * w0.z)));
        v[7] = fmaf(x3, w3.w, fmaf(x2, w2.w, fmaf(x1, w1.w, x0 * w0.w)));
      }
      {
        float x0 = xv2.x, x1 = xv2.y, x2 = xv2.z, x3 = xv2.w;
        v[8]  = fmaf(x3, w3.x, fmaf(x2, w2.x, fmaf(x1, w1.x, x0 * w0.x)));
        v[9]  = fmaf(x3, w3.y, fmaf(x2, w2.y, fmaf(x1, w1.y, x0 * w0.y)));
        v[10] = fmaf(x3, w3.z, fmaf(x2, w2.z, fmaf(x1, w1.z, x0 * w0.z)));
        v[11] = fmaf(x3, w3.w, fmaf(x2, w2.w, fmaf(x1, w1.w, x0 * w0.w)));
      }
      {
        float x0 = xv3.x, x1 = xv3.y, x2 = xv3.z, x3 = xv3.w;
        v[12] = fmaf(x3, w3.x, fmaf(x2, w2.x, fmaf(x1, w1.x, x0 * w0.x)));
        v[13] = fmaf(x3, w3.y, fmaf(x2, w2.y, fmaf(x1, w1.y, x0 * w0.y)));
        v[14] = fmaf(x3, w3.z, fmaf(x2, w2.z, fmaf(x1, w1.z, x0 * w0.z)));
        v[15] = fmaf(x3, w3.w, fmaf(x2, w2.w, fmaf(x1, w1.w, x0 * w0.w)));
      }

      float af = a_sh[B];
      float wgt;
      if (pass == 0) {
        wgt = af * 0.03125f;
      } else {
        // 4-way partial trees: chain depth 4+2 instead of 16
        float q0 = 0.f, q1 = 0.f, q2 = 0.f, q3 = 0.f;
        #pragma unroll
        for (int s = 0; s < 16; s += 4) {
          float d0 = v[s]     - mu[s];     q0 = fmaf(d0 * d0, i2s[s],     q0);
          float d1 = v[s + 1] - mu[s + 1]; q1 = fmaf(d1 * d1, i2s[s + 1], q1);
          float d2 = v[s + 2] - mu[s + 2]; q2 = fmaf(d2 * d2, i2s[s + 2], q2);
          float d3 = v[s + 3] - mu[s + 3]; q3 = fmaf(d3 * d3, i2s[s + 3], q3);
        }
        float lnap = bias - ((q0 + q1) + (q2 + q3));
        float mx = redmax32(lnap);
        float e = __expf(lnap - mx);
        float se = redsum32(e);
        float r2 = e * __builtin_amdgcn_rcpf(se);
        if (pass == 2) out[rbase + ((size_t)n * 288 + B) * 32 + c] = r2;
        wgt = r2 * af;
      }
      #pragma unroll
      for (int s = 0; s < 16; ++s) {
        float p = wgt * v[s];
        A1[s] += p;
        A2[s] = fmaf(p, v[s], A2[s]);
      }
      Ssum += wgt;
    }

    // ---- pre-reduce across the two wave halves, then LDS across 8 waves ----
    #pragma unroll
    for (int s = 0; s < 16; ++s) {
      A1[s] += __shfl_xor(A1[s], 32, 64);
      A2[s] += __shfl_xor(A2[s], 32, 64);
    }
    Ssum += __shfl_xor(Ssum, 32, 64);
    if ((tid & 63) < 32) {
      int col = (tid >> 6) * 32 + c;
      #pragma unroll
      for (int s = 0; s < 16; ++s) { red[s][col] = A1[s]; red[16 + s][col] = A2[s]; }
      red[32][col] = Ssum;
    }
    __syncthreads();

    // finalize mu/sigma: exactly one (c2,s) task per thread
    {
      int s = tid >> 5;
      int c2 = tid & 31;
      float a1 = 0.f, a2 = 0.f, ss = 0.f;
      #pragma unroll
      for (int ch = 0; ch < 8; ++ch) {
        int col = ch * 32 + c2;
        a1 += red[s][col];
        a2 += red[16 + s][col];
        ss += red[32][col];
      }
      float inv = __builtin_amdgcn_rcpf(ss + EPS);
      float m = a1 * inv;
      float Sc = ss * inv;
      float sg = fmaf(-m * m, 2.0f - Sc, a2 * inv) + EPS;   // sigma_sq
      mu_l[c2][s] = m;
      i2s_l[c2][s] = 0.5f * __builtin_amdgcn_rcpf(sg);
      hl_l[c2][s] = 0.5f * __logf(sg);
      if (s == 0) S_l[c2] = ss;
    }
    __syncthreads();

    if (tid < 32) {
      float sh = 0.f;
      #pragma unroll
      for (int s = 0; s < 16; ++s) sh += hl_l[tid][s];
      float cost = fmaf(beta_u[tid], 16.0f, sh) * S_l[tid];
      float z = LAMBDA * (beta_a[tid] - cost);
      float ao = __builtin_amdgcn_rcpf(1.0f + __expf(-z));
      aout_l[tid] = ao;
      lnao_l[tid] = __logf(ao);
    }
    __syncthreads();
  }

  // ---- outputs: row n = [mu (512) | a_out (32)], coalesced ----
  {
    int c2 = tid >> 4;
    int s = tid & 15;
    out[(size_t)n * 544 + tid] = mu_l[c2][s];
  }
  if (tid < 32) out[(size_t)n * 544 + 512 + tid] = aout_l[tid];
}

extern "C" void kernel_launch(void* const* d_in, const int* in_sizes, int n_in,
                              void* d_out, int out_size, void* d_ws, size_t ws_size,
                              hipStream_t stream) {
  const float* x  = (const float*)d_in[0];
  const float* w  = (const float*)d_in[1];
  const float* bu = (const float*)d_in[2];
  const float* ba = (const float*)d_in[3];
  float* out = (float*)d_out;
  convcaps_kernel<<<dim3(508), dim3(512), 0, stream>>>(x, w, bu, ba, out);
}

// Round 4
// 137.374 us; speedup vs baseline: 1.5195x; 1.0778x over previous
//
#include <hip/hip_runtime.h>
#include <math.h>

#define EPS 1e-8f
#define LAMBDA 1e-3f

// DPP lane-permute: executes in the VALU pipe (no LDS round trip, no addr calc).
template <int CTRL>
__device__ __forceinline__ float dppmov(float v) {
  return __int_as_float(__builtin_amdgcn_update_dpp(
      0, __float_as_int(v), CTRL, 0xF, 0xF, true));
}
// lane l -> lane l^16 within each 32-lane half (BitMode: xor=16, and=0x1F)
__device__ __forceinline__ float swz_xor16(float v) {
  return __int_as_float(__builtin_amdgcn_ds_swizzle(__float_as_int(v), 0x401F));
}

__device__ __forceinline__ float redsum32(float v) {
  v += dppmov<0xB1>(v);    // quad_perm [1,0,3,2] == xor 1
  v += dppmov<0x4E>(v);    // quad_perm [2,3,0,1] == xor 2
  v += dppmov<0x141>(v);   // row_half_mirror    == xor 7
  v += dppmov<0x140>(v);   // row_mirror         == xor 15
  v += swz_xor16(v);       // xor 16
  return v;
}
__device__ __forceinline__ float redmax32(float v) {
  v = fmaxf(v, dppmov<0xB1>(v));
  v = fmaxf(v, dppmov<0x4E>(v));
  v = fmaxf(v, dppmov<0x141>(v));
  v = fmaxf(v, dppmov<0x140>(v));
  v = fmaxf(v, swz_xor16(v));
  return v;
}

// One block per output row n (508 rows). 512 threads = 16 chunks x 32 c.
// Thread (chunk,c) owns output capsule c for B in [chunk*18, chunk*18+18).
//
// Softmax max-chain ELIMINATED: lnap = bias - acc with acc >= 0 and bias
// constant across the pass's 18 iterations; subtracting mx_bias =
// redmax32(bias) ONCE per pass guarantees lnap <= 0 (no exp overflow) and
// softmax is shift-invariant, so r is unchanged. Saves 5 dependent
// cross-lane steps + the exp dependency per iteration.
//
// w is prefetched one iteration ahead (unroll-2, static banks): ~200cy L2
// latency hidden under the previous iteration's ~350cy of compute.
//
// launch_bounds(512, 2): (512,4) forced an effective 64-VGPR cap and
// spilled (rounds 0-2). Occupancy is LDS-capped (60KB -> 2 blocks/CU) and
// grid-capped (508 blocks), so allowing up to 128 VGPRs costs nothing.
__launch_bounds__(512, 2)
__global__ void convcaps_kernel(const float* __restrict__ x,
                                const float* __restrict__ wgl,
                                const float* __restrict__ beta_u,
                                const float* __restrict__ beta_a,
                                float* __restrict__ out) {
  __shared__ float xr[288][16];       // pose patches, 18 KB
  __shared__ float a_sh[288];         // a/(a+EPS)
  __shared__ float red[33][256];      // per-wave partials (A1[16],A2[16],S)
  __shared__ float mu_l[32][17];      // +1 pad: stride 17 coprime 32
  __shared__ float i2s_l[32][17];     // 1/(2*sigma)
  __shared__ float hl_l[32][17];      // 0.5*ln(sigma)
  __shared__ float S_l[32];
  __shared__ float aout_l[32];
  __shared__ float lnao_l[32];

  const int tid = threadIdx.x;
  const int n = blockIdx.x;
  const int c = tid & 31;
  const int chunk = tid >> 5;         // 0..15

  // ---- stage 9 source rows (float4): xr[B][s], a_sh[B] ----
  for (int idx = tid; idx < 1224; idx += 512) {   // 9 * 136 float4
    int t = idx / 136;
    int e4 = idx - t * 136;
    int g = 9 * n + t;
    int bg = g / 2286;                 // 2286 = 9*254
    int ki = (g % 2286) / 762;         // 762 = 3*254
    int owp = g % 254;
    const float4* src = reinterpret_cast<const float4*>(x) +
                        (size_t)((bg * 256 + ki + owp) * 4) * 136;
    float4 val = src[e4];
    if (e4 < 128) reinterpret_cast<float4*>(&xr[0][0])[t * 128 + e4] = val;
    else          reinterpret_cast<float4*>(a_sh)[t * 8 + (e4 - 128)] = val;
  }
  __syncthreads();
  for (int e = tid; e < 288; e += 512) { float a = a_sh[e]; a_sh[e] = a / (a + EPS); }
  __syncthreads();

  float A1[16], A2[16], Ssum;
  float mu[16], i2s[16];
  const size_t rbase = 276352;         // 2*254*544
  const int Bbase = chunk * 18;

  for (int pass = 0; pass < 3; ++pass) {
    #pragma unroll
    for (int s = 0; s < 16; ++s) { A1[s] = 0.f; A2[s] = 0.f; }
    Ssum = 0.f;
    float bias = 0.f;
    if (pass > 0) {
      float Hl = 0.f;
      #pragma unroll
      for (int s = 0; s < 16; ++s) {
        mu[s] = mu_l[c][s];
        i2s[s] = i2s_l[c][s];
        Hl += hl_l[c][s];
      }
      bias = lnao_l[c] - Hl;
      bias -= redmax32(bias);          // once per pass: makes lnap <= 0 always
    }

    // per-iteration work; w0..w3 passed in from the prefetch banks
    auto process = [&](int i, float4 w0, float4 w1, float4 w2, float4 w3) {
      int B = Bbase + i;
      const float4* xp = reinterpret_cast<const float4*>(&xr[B][0]);
      float4 xv0 = xp[0], xv1 = xp[1], xv2 = xp[2], xv3 = xp[3];
      float v[16];
      {
        float x0 = xv0.x, x1 = xv0.y, x2 = xv0.z, x3 = xv0.w;
        v[0] = fmaf(x3, w3.x, fmaf(x2, w2.x, fmaf(x1, w1.x, x0 * w0.x)));
        v[1] = fmaf(x3, w3.y, fmaf(x2, w2.y, fmaf(x1, w1.y, x0 * w0.y)));
        v[2] = fmaf(x3, w3.z, fmaf(x2, w2.z, fmaf(x1, w1.z, x0 * w0.z)));
        v[3] = fmaf(x3, w3.w, fmaf(x2, w2.w, fmaf(x1, w1.w, x0 * w0.w)));
      }
      {
        float x0 = xv1.x, x1 = xv1.y, x2 = xv1.z, x3 = xv1.w;
        v[4] = fmaf(x3, w3.x, fmaf(x2, w2.x, fmaf(x1, w1.x, x0 * w0.x)));
        v[5] = fmaf(x3, w3.y, fmaf(x2, w2.y, fmaf(x1, w1.y, x0 * w0.y)));
        v[6] = fmaf(x3, w3.z, fmaf(x2, w2.z, fmaf(x1, w1.z, x0 * w0.z)));
        v[7] = fmaf(x3, w3.w, fmaf(x2, w2.w, fmaf(x1, w1.w, x0 * w0.w)));
      }
      {
        float x0 = xv2.x, x1 = xv2.y, x2 = xv2.z, x3 = xv2.w;
        v[8]  = fmaf(x3, w3.x, fmaf(x2, w2.x, fmaf(x1, w1.x, x0 * w0.x)));
        v[9]  = fmaf(x3, w3.y, fmaf(x2, w2.y, fmaf(x1, w1.y, x0 * w0.y)));
        v[10] = fmaf(x3, w3.z, fmaf(x2, w2.z, fmaf(x1, w1.z, x0 * w0.z)));
        v[11] = fmaf(x3, w3.w, fmaf(x2, w2.w, fmaf(x1, w1.w, x0 * w0.w)));
      }
      {
        float x0 = xv3.x, x1 = xv3.y, x2 = xv3.z, x3 = xv3.w;
        v[12] = fmaf(x3, w3.x, fmaf(x2, w2.x, fmaf(x1, w1.x, x0 * w0.x)));
        v[13] = fmaf(x3, w3.y, fmaf(x2, w2.y, fmaf(x1, w1.y, x0 * w0.y)));
        v[14] = fmaf(x3, w3.z, fmaf(x2, w2.z, fmaf(x1, w1.z, x0 * w0.z)));
        v[15] = fmaf(x3, w3.w, fmaf(x2, w2.w, fmaf(x1, w1.w, x0 * w0.w)));
      }

      float af = a_sh[B];
      float wgt;
      if (pass == 0) {
        wgt = af * 0.03125f;
      } else {
        // 4-way partial trees: chain depth 4+2 instead of 16
        float q0 = 0.f, q1 = 0.f, q2 = 0.f, q3 = 0.f;
        #pragma unroll
        for (int s = 0; s < 16; s += 4) {
          float d0 = v[s]     - mu[s];     q0 = fmaf(d0 * d0, i2s[s],     q0);
          float d1 = v[s + 1] - mu[s + 1]; q1 = fmaf(d1 * d1, i2s[s + 1], q1);
          float d2 = v[s + 2] - mu[s + 2]; q2 = fmaf(d2 * d2, i2s[s + 2], q2);
          float d3 = v[s + 3] - mu[s + 3]; q3 = fmaf(d3 * d3, i2s[s + 3], q3);
        }
        float lnap = bias - ((q0 + q1) + (q2 + q3));   // <= 0 by construction
        float e = __expf(lnap);                        // no max chain needed
        float se = redsum32(e);
        float r2 = e * __builtin_amdgcn_rcpf(se + 1e-35f);
        if (pass == 2) out[rbase + ((size_t)n * 288 + B) * 32 + c] = r2;
        wgt = r2 * af;
      }
      #pragma unroll
      for (int s = 0; s < 16; ++s) {
        float p = wgt * v[s];
        A1[s] += p;
        A2[s] = fmaf(p, v[s], A2[s]);
      }
      Ssum += wgt;
    };

    // ---- software-pipelined B loop: w prefetched one iteration ahead ----
    const float4* wp = reinterpret_cast<const float4*>(wgl) + ((size_t)(Bbase * 32 + c)) * 4;
    // bank A <- w(i=0)
    float4 wa0 = wp[0], wa1 = wp[1], wa2 = wp[2], wa3 = wp[3];
    for (int ii = 0; ii < 9; ++ii) {
      int iA = 2 * ii, iB = iA + 1;
      // bank B <- w(iB), issued before process(iA) so latency hides under it
      const float4* wpb = wp + (size_t)iB * 128;   // +32*16 floats per B
      float4 wb0 = wpb[0], wb1 = wpb[1], wb2 = wpb[2], wb3 = wpb[3];
      process(iA, wa0, wa1, wa2, wa3);
      if (ii < 8) {
        const float4* wpa = wp + (size_t)(iB + 1) * 128;
        wa0 = wpa[0]; wa1 = wpa[1]; wa2 = wpa[2]; wa3 = wpa[3];
      }
      process(iB, wb0, wb1, wb2, wb3);
    }

    // ---- pre-reduce across the two wave halves, then LDS across 8 waves ----
    #pragma unroll
    for (int s = 0; s < 16; ++s) {
      A1[s] += __shfl_xor(A1[s], 32, 64);
      A2[s] += __shfl_xor(A2[s], 32, 64);
    }
    Ssum += __shfl_xor(Ssum, 32, 64);
    if ((tid & 63) < 32) {
      int col = (tid >> 6) * 32 + c;
      #pragma unroll
      for (int s = 0; s < 16; ++s) { red[s][col] = A1[s]; red[16 + s][col] = A2[s]; }
      red[32][col] = Ssum;
    }
    __syncthreads();

    // finalize mu/sigma: exactly one (c2,s) task per thread
    {
      int s = tid >> 5;
      int c2 = tid & 31;
      float a1 = 0.f, a2 = 0.f, ss = 0.f;
      #pragma unroll
      for (int ch = 0; ch < 8; ++ch) {
        int col = ch * 32 + c2;
        a1 += red[s][col];
        a2 += red[16 + s][col];
        ss += red[32][col];
      }
      float inv = __builtin_amdgcn_rcpf(ss + EPS);
      float m = a1 * inv;
      float Sc = ss * inv;
      float sg = fmaf(-m * m, 2.0f - Sc, a2 * inv) + EPS;   // sigma_sq
      mu_l[c2][s] = m;
      i2s_l[c2][s] = 0.5f * __builtin_amdgcn_rcpf(sg);
      hl_l[c2][s] = 0.5f * __logf(sg);
      if (s == 0) S_l[c2] = ss;
    }
    __syncthreads();

    if (tid < 32) {
      float sh = 0.f;
      #pragma unroll
      for (int s = 0; s < 16; ++s) sh += hl_l[tid][s];
      float cost = fmaf(beta_u[tid], 16.0f, sh) * S_l[tid];
      float z = LAMBDA * (beta_a[tid] - cost);
      float ao = __builtin_amdgcn_rcpf(1.0f + __expf(-z));
      aout_l[tid] = ao;
      lnao_l[tid] = __logf(ao);
    }
    __syncthreads();
  }

  // ---- outputs: row n = [mu (512) | a_out (32)], coalesced ----
  {
    int c2 = tid >> 4;
    int s = tid & 15;
    out[(size_t)n * 544 + tid] = mu_l[c2][s];
  }
  if (tid < 32) out[(size_t)n * 544 + 512 + tid] = aout_l[tid];
}

extern "C" void kernel_launch(void* const* d_in, const int* in_sizes, int n_in,
                              void* d_out, int out_size, void* d_ws, size_t ws_size,
                              hipStream_t stream) {
  const float* x  = (const float*)d_in[0];
  const float* w  = (const float*)d_in[1];
  const float* bu = (const float*)d_in[2];
  const float* ba = (const float*)d_in[3];
  float* out = (float*)d_out;
  convcaps_kernel<<<dim3(508), dim3(512), 0, stream>>>(x, w, bu, ba, out);
}

// Round 5
// 129.783 us; speedup vs baseline: 1.6084x; 1.0585x over previous
//
#include <hip/hip_runtime.h>
#include <math.h>

#define EPS 1e-8f
#define LAMBDA 1e-3f
#define LOG2E 1.44269504088896f

typedef float f2 __attribute__((ext_vector_type(2)));
__device__ __forceinline__ f2 f2s(float x) { return (f2){x, x}; }
__device__ __forceinline__ f2 pkfma(f2 a, f2 b, f2 c) {
  return __builtin_elementwise_fma(a, b, c);
}

// DPP lane-permute: executes in the VALU pipe (no LDS round trip, no addr calc).
template <int CTRL>
__device__ __forceinline__ float dppmov(float v) {
  return __int_as_float(__builtin_amdgcn_update_dpp(
      0, __float_as_int(v), CTRL, 0xF, 0xF, true));
}
// lane l -> lane l^16 within each 32-lane half (BitMode: xor=16, and=0x1F)
__device__ __forceinline__ float swz_xor16(float v) {
  return __int_as_float(__builtin_amdgcn_ds_swizzle(__float_as_int(v), 0x401F));
}

__device__ __forceinline__ float redsum32(float v) {
  v += dppmov<0xB1>(v);    // quad_perm [1,0,3,2] == xor 1
  v += dppmov<0x4E>(v);    // quad_perm [2,3,0,1] == xor 2
  v += dppmov<0x141>(v);   // row_half_mirror    == xor 7
  v += dppmov<0x140>(v);   // row_mirror         == xor 15
  v += swz_xor16(v);       // xor 16
  return v;
}
__device__ __forceinline__ float redmax32(float v) {
  v = fmaxf(v, dppmov<0xB1>(v));
  v = fmaxf(v, dppmov<0x4E>(v));
  v = fmaxf(v, dppmov<0x141>(v));
  v = fmaxf(v, dppmov<0x140>(v));
  v = fmaxf(v, swz_xor16(v));
  return v;
}

// One block per output row n (508 rows). 512 threads = 16 chunks x 32 c.
// Thread (chunk,c) owns output capsule c for B in [chunk*18, chunk*18+18).
//
// Hot-loop math expressed on 2-wide float vectors so the backend selects
// packed fp32 VOP3P (v_pk_fma_f32 etc, full-rate on CDNA): mat4x4 64->32,
// A-update 48->24, q-tree 32->~20 issued instrs per iteration.
//
// Softmax: max-chain eliminated (bias - redmax32(bias) once per pass makes
// lnap <= 0); exp done in log2 domain (i2s/bias pre-scaled by LOG2E) so the
// iteration cost is one bare v_exp_f32; e*af precomputed so only rcp+mul
// trail the redsum.
//
// launch_bounds(512, 2): (512,4) forced an effective 64-VGPR cap and
// spilled (rounds 0-2). Occupancy is LDS-capped (60KB -> 2 blocks/CU) and
// grid-capped (508 blocks); VGPR must stay <=128 to keep 2 blocks/CU.
__launch_bounds__(512, 2)
__global__ void convcaps_kernel(const float* __restrict__ x,
                                const float* __restrict__ wgl,
                                const float* __restrict__ beta_u,
                                const float* __restrict__ beta_a,
                                float* __restrict__ out) {
  __shared__ float xr[288][16];       // pose patches, 18 KB
  __shared__ float a_sh[288];         // a/(a+EPS)
  __shared__ float red[33][256];      // per-wave partials (A1[16],A2[16],S)
  __shared__ float mu_l[32][18];      // +2 pad: rows 8B-aligned for b64 reads,
  __shared__ float i2s_l[32][18];     //   stride-18 is a free 2-way conflict
  __shared__ float hl_l[32][18];      // 0.5*ln(sigma)
  __shared__ float S_l[32];
  __shared__ float aout_l[32];
  __shared__ float lnao_l[32];

  const int tid = threadIdx.x;
  const int n = blockIdx.x;
  const int c = tid & 31;
  const int chunk = tid >> 5;         // 0..15

  // ---- stage 9 source rows (float4): xr[B][s], a_sh[B] ----
  for (int idx = tid; idx < 1224; idx += 512) {   // 9 * 136 float4
    int t = idx / 136;
    int e4 = idx - t * 136;
    int g = 9 * n + t;
    int bg = g / 2286;                 // 2286 = 9*254
    int ki = (g % 2286) / 762;         // 762 = 3*254
    int owp = g % 254;
    const float4* src = reinterpret_cast<const float4*>(x) +
                        (size_t)((bg * 256 + ki + owp) * 4) * 136;
    float4 val = src[e4];
    if (e4 < 128) reinterpret_cast<float4*>(&xr[0][0])[t * 128 + e4] = val;
    else          reinterpret_cast<float4*>(a_sh)[t * 8 + (e4 - 128)] = val;
  }
  __syncthreads();
  for (int e = tid; e < 288; e += 512) { float a = a_sh[e]; a_sh[e] = a / (a + EPS); }
  __syncthreads();

  f2 A1[8], A2[8];
  float Ssum;
  f2 mu2[8], i2s2[8];                 // i2s2 pre-scaled by LOG2E
  const size_t rbase = 276352;         // 2*254*544
  const int Bbase = chunk * 18;

  for (int pass = 0; pass < 3; ++pass) {
    #pragma unroll
    for (int j = 0; j < 8; ++j) { A1[j] = (f2){0.f, 0.f}; A2[j] = (f2){0.f, 0.f}; }
    Ssum = 0.f;
    float bias2 = 0.f;
    if (pass > 0) {
      const f2* murow = reinterpret_cast<const f2*>(&mu_l[c][0]);
      const f2* isrow = reinterpret_cast<const f2*>(&i2s_l[c][0]);
      float Hl = 0.f;
      #pragma unroll
      for (int j = 0; j < 8; ++j) {
        mu2[j] = murow[j];
        i2s2[j] = isrow[j];
        Hl += hl_l[c][2 * j] + hl_l[c][2 * j + 1];
      }
      float bias = lnao_l[c] - Hl;
      bias -= redmax32(bias);          // once per pass: makes lnap <= 0 always
      bias2 = bias * LOG2E;            // log2 domain
    }

    // per-iteration work; w0..w3 passed in from the prefetch banks
    auto process = [&](int i, float4 w0, float4 w1, float4 w2, float4 w3) {
      int B = Bbase + i;
      f2 w0a = {w0.x, w0.y}, w0b = {w0.z, w0.w};
      f2 w1a = {w1.x, w1.y}, w1b = {w1.z, w1.w};
      f2 w2a = {w2.x, w2.y}, w2b = {w2.z, w2.w};
      f2 w3a = {w3.x, w3.y}, w3b = {w3.z, w3.w};
      const float4* xp = reinterpret_cast<const float4*>(&xr[B][0]);
      float4 xv0 = xp[0], xv1 = xp[1], xv2 = xp[2], xv3 = xp[3];
      f2 v2[8];
      {
        f2 ta = f2s(xv0.x) * w0a; f2 tb = f2s(xv0.x) * w0b;
        ta = pkfma(f2s(xv0.y), w1a, ta); tb = pkfma(f2s(xv0.y), w1b, tb);
        ta = pkfma(f2s(xv0.z), w2a, ta); tb = pkfma(f2s(xv0.z), w2b, tb);
        v2[0] = pkfma(f2s(xv0.w), w3a, ta); v2[1] = pkfma(f2s(xv0.w), w3b, tb);
      }
      {
        f2 ta = f2s(xv1.x) * w0a; f2 tb = f2s(xv1.x) * w0b;
        ta = pkfma(f2s(xv1.y), w1a, ta); tb = pkfma(f2s(xv1.y), w1b, tb);
        ta = pkfma(f2s(xv1.z), w2a, ta); tb = pkfma(f2s(xv1.z), w2b, tb);
        v2[2] = pkfma(f2s(xv1.w), w3a, ta); v2[3] = pkfma(f2s(xv1.w), w3b, tb);
      }
      {
        f2 ta = f2s(xv2.x) * w0a; f2 tb = f2s(xv2.x) * w0b;
        ta = pkfma(f2s(xv2.y), w1a, ta); tb = pkfma(f2s(xv2.y), w1b, tb);
        ta = pkfma(f2s(xv2.z), w2a, ta); tb = pkfma(f2s(xv2.z), w2b, tb);
        v2[4] = pkfma(f2s(xv2.w), w3a, ta); v2[5] = pkfma(f2s(xv2.w), w3b, tb);
      }
      {
        f2 ta = f2s(xv3.x) * w0a; f2 tb = f2s(xv3.x) * w0b;
        ta = pkfma(f2s(xv3.y), w1a, ta); tb = pkfma(f2s(xv3.y), w1b, tb);
        ta = pkfma(f2s(xv3.z), w2a, ta); tb = pkfma(f2s(xv3.z), w2b, tb);
        v2[6] = pkfma(f2s(xv3.w), w3a, ta); v2[7] = pkfma(f2s(xv3.w), w3b, tb);
      }

      float af = a_sh[B];
      float wgt;
      if (pass == 0) {
        wgt = af * 0.03125f;
      } else {
        // packed quadratic form, two f2 partial trees (4 scalar partials)
        f2 qa = {0.f, 0.f}, qb = {0.f, 0.f};
        #pragma unroll
        for (int j = 0; j < 8; j += 2) {
          f2 d0 = v2[j] - mu2[j];
          qa = pkfma(d0 * i2s2[j], d0, qa);
          f2 d1 = v2[j + 1] - mu2[j + 1];
          qb = pkfma(d1 * i2s2[j + 1], d1, qb);
        }
        float acc = (qa.x + qb.x) + (qa.y + qb.y);
        float lnap = bias2 - acc;                   // <= 0, log2 domain
        float e;
        asm("v_exp_f32 %0, %1" : "=v"(e) : "v"(lnap));
        float ea = e * af;                          // independent of reduce
        float se = redsum32(e);
        float t = __builtin_amdgcn_rcpf(se + 1e-35f);
        wgt = ea * t;                               // only rcp+mul after reduce
        if (pass == 2) out[rbase + ((size_t)n * 288 + B) * 32 + c] = e * t;
      }
      f2 wgt2 = f2s(wgt);
      #pragma unroll
      for (int j = 0; j < 8; ++j) {
        f2 p = wgt2 * v2[j];
        A1[j] += p;
        A2[j] = pkfma(p, v2[j], A2[j]);
      }
      Ssum += wgt;
    };

    // ---- software-pipelined B loop: w prefetched one iteration ahead ----
    const float4* wp = reinterpret_cast<const float4*>(wgl) + ((size_t)(Bbase * 32 + c)) * 4;
    // bank A <- w(i=0)
    float4 wa0 = wp[0], wa1 = wp[1], wa2 = wp[2], wa3 = wp[3];
    for (int ii = 0; ii < 9; ++ii) {
      int iA = 2 * ii, iB = iA + 1;
      // bank B <- w(iB), issued before process(iA) so latency hides under it
      const float4* wpb = wp + (size_t)iB * 128;   // +32*16 floats per B
      float4 wb0 = wpb[0], wb1 = wpb[1], wb2 = wpb[2], wb3 = wpb[3];
      process(iA, wa0, wa1, wa2, wa3);
      if (ii < 8) {
        const float4* wpa = wp + (size_t)(iB + 1) * 128;
        wa0 = wpa[0]; wa1 = wpa[1]; wa2 = wpa[2]; wa3 = wpa[3];
      }
      process(iB, wb0, wb1, wb2, wb3);
    }

    // ---- pre-reduce across the two wave halves, then LDS across 8 waves ----
    #pragma unroll
    for (int j = 0; j < 8; ++j) {
      A1[j].x += __shfl_xor(A1[j].x, 32, 64);
      A1[j].y += __shfl_xor(A1[j].y, 32, 64);
      A2[j].x += __shfl_xor(A2[j].x, 32, 64);
      A2[j].y += __shfl_xor(A2[j].y, 32, 64);
    }
    Ssum += __shfl_xor(Ssum, 32, 64);
    if ((tid & 63) < 32) {
      int col = (tid >> 6) * 32 + c;
      #pragma unroll
      for (int j = 0; j < 8; ++j) {
        red[2 * j][col] = A1[j].x;
        red[2 * j + 1][col] = A1[j].y;
        red[16 + 2 * j][col] = A2[j].x;
        red[17 + 2 * j][col] = A2[j].y;
      }
      red[32][col] = Ssum;
    }
    __syncthreads();

    // finalize mu/sigma: exactly one (c2,s) task per thread
    {
      int s = tid >> 5;
      int c2 = tid & 31;
      float a1 = 0.f, a2 = 0.f, ss = 0.f;
      #pragma unroll
      for (int ch = 0; ch < 8; ++ch) {
        int col = ch * 32 + c2;
        a1 += red[s][col];
        a2 += red[16 + s][col];
        ss += red[32][col];
      }
      float inv = __builtin_amdgcn_rcpf(ss + EPS);
      float m = a1 * inv;
      float Sc = ss * inv;
      float sg = fmaf(-m * m, 2.0f - Sc, a2 * inv) + EPS;   // sigma_sq
      mu_l[c2][s] = m;
      i2s_l[c2][s] = (0.5f * LOG2E) * __builtin_amdgcn_rcpf(sg);  // log2 domain
      hl_l[c2][s] = 0.5f * __logf(sg);
      if (s == 0) S_l[c2] = ss;
    }
    __syncthreads();

    if (tid < 32) {
      float sh = 0.f;
      #pragma unroll
      for (int s = 0; s < 16; ++s) sh += hl_l[tid][s];
      float cost = fmaf(beta_u[tid], 16.0f, sh) * S_l[tid];
      float z = LAMBDA * (beta_a[tid] - cost);
      float ao = __builtin_amdgcn_rcpf(1.0f + __expf(-z));
      aout_l[tid] = ao;
      lnao_l[tid] = __logf(ao);
    }
    __syncthreads();
  }

  // ---- outputs: row n = [mu (512) | a_out (32)], coalesced ----
  {
    int c2 = tid >> 4;
    int s = tid & 15;
    out[(size_t)n * 544 + tid] = mu_l[c2][s];
  }
  if (tid < 32) out[(size_t)n * 544 + 512 + tid] = aout_l[tid];
}

extern "C" void kernel_launch(void* const* d_in, const int* in_sizes, int n_in,
                              void* d_out, int out_size, void* d_ws, size_t ws_size,
                              hipStream_t stream) {
  const float* x  = (const float*)d_in[0];
  const float* w  = (const float*)d_in[1];
  const float* bu = (const float*)d_in[2];
  const float* ba = (const float*)d_in[3];
  float* out = (float*)d_out;
  convcaps_kernel<<<dim3(508), dim3(512), 0, stream>>>(x, w, bu, ba, out);
}

// Round 6
// 128.249 us; speedup vs baseline: 1.6276x; 1.0120x over previous
//
#include <hip/hip_runtime.h>
#include <math.h>

#define EPS 1e-8f
#define LAMBDA 1e-3f
#define LOG2E 1.44269504088896f

typedef float f2 __attribute__((ext_vector_type(2)));
__device__ __forceinline__ f2 f2s(float x) { return (f2){x, x}; }
__device__ __forceinline__ f2 pkfma(f2 a, f2 b, f2 c) {
  return __builtin_elementwise_fma(a, b, c);
}

// DPP lane-permute: executes in the VALU pipe (no LDS round trip, no addr calc).
template <int CTRL>
__device__ __forceinline__ float dppmov(float v) {
  return __int_as_float(__builtin_amdgcn_update_dpp(
      0, __float_as_int(v), CTRL, 0xF, 0xF, true));
}
// lane l -> lane l^16 within each 32-lane half (BitMode: xor=16, and=0x1F)
__device__ __forceinline__ float swz_xor16(float v) {
  return __int_as_float(__builtin_amdgcn_ds_swizzle(__float_as_int(v), 0x401F));
}

__device__ __forceinline__ float redsum32(float v) {
  v += dppmov<0xB1>(v);    // quad_perm [1,0,3,2] == xor 1
  v += dppmov<0x4E>(v);    // quad_perm [2,3,0,1] == xor 2
  v += dppmov<0x141>(v);   // row_half_mirror    == xor 7
  v += dppmov<0x140>(v);   // row_mirror         == xor 15
  v += swz_xor16(v);       // xor 16
  return v;
}
__device__ __forceinline__ float redmax32(float v) {
  v = fmaxf(v, dppmov<0xB1>(v));
  v = fmaxf(v, dppmov<0x4E>(v));
  v = fmaxf(v, dppmov<0x141>(v));
  v = fmaxf(v, dppmov<0x140>(v));
  v = fmaxf(v, swz_xor16(v));
  return v;
}

// 4x4 pose matmul on packed f2 lanes: v2[8] = x(4x4) @ w(4x4), row-major.
__device__ __forceinline__ void mat8(const float* __restrict__ xrow,
                                     float4 w0, float4 w1, float4 w2, float4 w3,
                                     f2 (&v2)[8]) {
  const float4* xp = reinterpret_cast<const float4*>(xrow);
  float4 xv0 = xp[0], xv1 = xp[1], xv2_ = xp[2], xv3 = xp[3];
  f2 w0a = {w0.x, w0.y}, w0b = {w0.z, w0.w};
  f2 w1a = {w1.x, w1.y}, w1b = {w1.z, w1.w};
  f2 w2a = {w2.x, w2.y}, w2b = {w2.z, w2.w};
  f2 w3a = {w3.x, w3.y}, w3b = {w3.z, w3.w};
  {
    f2 ta = f2s(xv0.x) * w0a; f2 tb = f2s(xv0.x) * w0b;
    ta = pkfma(f2s(xv0.y), w1a, ta); tb = pkfma(f2s(xv0.y), w1b, tb);
    ta = pkfma(f2s(xv0.z), w2a, ta); tb = pkfma(f2s(xv0.z), w2b, tb);
    v2[0] = pkfma(f2s(xv0.w), w3a, ta); v2[1] = pkfma(f2s(xv0.w), w3b, tb);
  }
  {
    f2 ta = f2s(xv1.x) * w0a; f2 tb = f2s(xv1.x) * w0b;
    ta = pkfma(f2s(xv1.y), w1a, ta); tb = pkfma(f2s(xv1.y), w1b, tb);
    ta = pkfma(f2s(xv1.z), w2a, ta); tb = pkfma(f2s(xv1.z), w2b, tb);
    v2[2] = pkfma(f2s(xv1.w), w3a, ta); v2[3] = pkfma(f2s(xv1.w), w3b, tb);
  }
  {
    f2 ta = f2s(xv2_.x) * w0a; f2 tb = f2s(xv2_.x) * w0b;
    ta = pkfma(f2s(xv2_.y), w1a, ta); tb = pkfma(f2s(xv2_.y), w1b, tb);
    ta = pkfma(f2s(xv2_.z), w2a, ta); tb = pkfma(f2s(xv2_.z), w2b, tb);
    v2[4] = pkfma(f2s(xv2_.w), w3a, ta); v2[5] = pkfma(f2s(xv2_.w), w3b, tb);
  }
  {
    f2 ta = f2s(xv3.x) * w0a; f2 tb = f2s(xv3.x) * w0b;
    ta = pkfma(f2s(xv3.y), w1a, ta); tb = pkfma(f2s(xv3.y), w1b, tb);
    ta = pkfma(f2s(xv3.z), w2a, ta); tb = pkfma(f2s(xv3.z), w2b, tb);
    v2[6] = pkfma(f2s(xv3.w), w3a, ta); v2[7] = pkfma(f2s(xv3.w), w3b, tb);
  }
}

// One block per output row n (508 rows). 512 threads = 16 chunks x 32 c.
// Thread (chunk,c) owns output capsule c for B in [chunk*18, chunk*18+18).
//
// Passes 1/2 are software-pipelined with a one-iteration skew: iteration i's
// redsum tree (5 dependent cross-lane steps) overlaps iteration i-1's
// A-update (24 independent pk ops) -- the only serial chain TLP couldn't
// hide at 4 waves/SIMD. Rotating vA/vB register banks avoid copies.
//
// Quadratic form factored: (v-mu)^2*i2s = v*(i2s*v + m2) + k with
// m2 = -2*mu*i2s (stored instead of mu) and k = sum(mu^2*i2s) folded into
// the bias -> 2 pk ops per f2 element instead of 3.
//
// launch_bounds(512, 2): caps VGPR at 128 (2 blocks/CU); (512,4) forced an
// effective 64-cap and spilled (rounds 0-2). Spills show up as WRITE_SIZE
// above the 19.4 MB output floor.
__launch_bounds__(512, 2)
__global__ void convcaps_kernel(const float* __restrict__ x,
                                const float* __restrict__ wgl,
                                const float* __restrict__ beta_u,
                                const float* __restrict__ beta_a,
                                float* __restrict__ out) {
  __shared__ float xr[288][16];       // pose patches, 18 KB
  __shared__ float a_sh[288];         // a/(a+EPS)
  __shared__ float red[33][256];      // per-wave partials (A1[16],A2[16],S)
  __shared__ float mu_l[32][18];      // +2 pad: rows 8B-aligned for b64 reads
  __shared__ float i2s_l[32][18];     // LOG2E/(2*sigma)
  __shared__ float hl_l[32][18];      // 0.5*ln(sigma)
  __shared__ float S_l[32];
  __shared__ float aout_l[32];
  __shared__ float lnao_l[32];

  const int tid = threadIdx.x;
  const int n = blockIdx.x;
  const int c = tid & 31;
  const int chunk = tid >> 5;         // 0..15

  // ---- stage 9 source rows (float4): xr[B][s], a_sh[B] ----
  for (int idx = tid; idx < 1224; idx += 512) {   // 9 * 136 float4
    int t = idx / 136;
    int e4 = idx - t * 136;
    int g = 9 * n + t;
    int bg = g / 2286;                 // 2286 = 9*254
    int ki = (g % 2286) / 762;         // 762 = 3*254
    int owp = g % 254;
    const float4* src = reinterpret_cast<const float4*>(x) +
                        (size_t)((bg * 256 + ki + owp) * 4) * 136;
    float4 val = src[e4];
    if (e4 < 128) reinterpret_cast<float4*>(&xr[0][0])[t * 128 + e4] = val;
    else          reinterpret_cast<float4*>(a_sh)[t * 8 + (e4 - 128)] = val;
  }
  __syncthreads();
  for (int e = tid; e < 288; e += 512) { float a = a_sh[e]; a_sh[e] = a / (a + EPS); }
  __syncthreads();

  f2 A1[8], A2[8];
  float Ssum;
  f2 m2[8], i2s2[8];                  // m2 = -2*mu*i2s; i2s pre-scaled LOG2E
  float bias3 = 0.f;
  const int Bbase = chunk * 18;
  const float4* wp = reinterpret_cast<const float4*>(wgl) + ((size_t)(Bbase * 32 + c)) * 4;
  float* rowout = out + 276352 + ((size_t)n * 288 + Bbase) * 32 + c;   // r output

  auto accum = [&](const f2 (&v2)[8], float wgt) {
    f2 wg = f2s(wgt);
    #pragma unroll
    for (int j = 0; j < 8; ++j) {
      f2 p = wg * v2[j];
      A1[j] += p;
      A2[j] = pkfma(p, v2[j], A2[j]);
    }
    Ssum += wgt;
  };

  auto qexp = [&](const f2 (&v2)[8]) -> float {
    f2 qa = {0.f, 0.f}, qb = {0.f, 0.f};
    #pragma unroll
    for (int j = 0; j < 8; j += 2) {
      f2 t0 = pkfma(v2[j], i2s2[j], m2[j]);
      qa = pkfma(v2[j], t0, qa);
      f2 t1 = pkfma(v2[j + 1], i2s2[j + 1], m2[j + 1]);
      qb = pkfma(v2[j + 1], t1, qb);
    }
    float acc = (qa.x + qb.x) + (qa.y + qb.y);
    float lnap = bias3 - acc;           // == log2-domain bias - mahalanobis, <= 0
    float e;
    asm("v_exp_f32 %0, %1" : "=v"(e) : "v"(lnap));
    return e;
  };

  auto finalize = [&]() {
    // pre-reduce across the two wave halves, then LDS across 8 waves
    #pragma unroll
    for (int j = 0; j < 8; ++j) {
      A1[j].x += __shfl_xor(A1[j].x, 32, 64);
      A1[j].y += __shfl_xor(A1[j].y, 32, 64);
      A2[j].x += __shfl_xor(A2[j].x, 32, 64);
      A2[j].y += __shfl_xor(A2[j].y, 32, 64);
    }
    Ssum += __shfl_xor(Ssum, 32, 64);
    if ((tid & 63) < 32) {
      int col = (tid >> 6) * 32 + c;
      #pragma unroll
      for (int j = 0; j < 8; ++j) {
        red[2 * j][col] = A1[j].x;
        red[2 * j + 1][col] = A1[j].y;
        red[16 + 2 * j][col] = A2[j].x;
        red[17 + 2 * j][col] = A2[j].y;
      }
      red[32][col] = Ssum;
    }
    __syncthreads();
    {
      int s = tid >> 5;
      int c2 = tid & 31;
      float a1 = 0.f, a2 = 0.f, ss = 0.f;
      #pragma unroll
      for (int ch = 0; ch < 8; ++ch) {
        int col = ch * 32 + c2;
        a1 += red[s][col];
        a2 += red[16 + s][col];
        ss += red[32][col];
      }
      float inv = __builtin_amdgcn_rcpf(ss + EPS);
      float m = a1 * inv;
      float Sc = ss * inv;
      float sg = fmaf(-m * m, 2.0f - Sc, a2 * inv) + EPS;   // sigma_sq
      mu_l[c2][s] = m;
      i2s_l[c2][s] = (0.5f * LOG2E) * __builtin_amdgcn_rcpf(sg);  // log2 domain
      hl_l[c2][s] = 0.5f * __logf(sg);
      if (s == 0) S_l[c2] = ss;
    }
    __syncthreads();
    if (tid < 32) {
      float sh = 0.f;
      #pragma unroll
      for (int s = 0; s < 16; ++s) sh += hl_l[tid][s];
      float cost = fmaf(beta_u[tid], 16.0f, sh) * S_l[tid];
      float z = LAMBDA * (beta_a[tid] - cost);
      float ao = __builtin_amdgcn_rcpf(1.0f + __expf(-z));
      aout_l[tid] = ao;
      lnao_l[tid] = __logf(ao);
    }
    __syncthreads();
  };

  // ================= pass 0: wgt = a/32, no softmax =================
  {
    #pragma unroll
    for (int j = 0; j < 8; ++j) { A1[j] = (f2){0.f, 0.f}; A2[j] = (f2){0.f, 0.f}; }
    Ssum = 0.f;
    float4 wa0 = wp[0], wa1 = wp[1], wa2 = wp[2], wa3 = wp[3];
    for (int i = 0; i < 18; ++i) {
      float4 w0 = wa0, w1 = wa1, w2 = wa2, w3 = wa3;
      if (i < 17) {
        const float4* nx = wp + (size_t)(i + 1) * 128;
        wa0 = nx[0]; wa1 = nx[1]; wa2 = nx[2]; wa3 = nx[3];
      }
      f2 v2[8];
      mat8(&xr[Bbase + i][0], w0, w1, w2, w3, v2);
      accum(v2, a_sh[Bbase + i] * 0.03125f);
    }
    finalize();
  }

  // ================= passes 1,2: pipelined softmax loop =================
  for (int pass = 1; pass < 3; ++pass) {
    #pragma unroll
    for (int j = 0; j < 8; ++j) { A1[j] = (f2){0.f, 0.f}; A2[j] = (f2){0.f, 0.f}; }
    Ssum = 0.f;
    {
      const f2* murow = reinterpret_cast<const f2*>(&mu_l[c][0]);
      const f2* isrow = reinterpret_cast<const f2*>(&i2s_l[c][0]);
      f2 kacc = {0.f, 0.f};
      float Hl = 0.f;
      #pragma unroll
      for (int j = 0; j < 8; ++j) {
        f2 mu = murow[j];
        f2 is = isrow[j];
        i2s2[j] = is;
        f2 mis = mu * is;
        m2[j] = f2s(-2.f) * mis;
        kacc = pkfma(mis, mu, kacc);        // sum mu^2*i2s (log2 domain)
        Hl += hl_l[c][2 * j] + hl_l[c][2 * j + 1];
      }
      float bias = lnao_l[c] - Hl;
      bias -= redmax32(bias);               // once per pass: lnap <= 0 always
      bias3 = bias * LOG2E - (kacc.x + kacc.y);
    }
    const bool doStore = (pass == 2);

    float4 wa0 = wp[0], wa1 = wp[1], wa2 = wp[2], wa3 = wp[3];
    float4 wb0, wb1, wb2, wb3;
    { const float4* nx = wp + 128; wb0 = nx[0]; wb1 = nx[1]; wb2 = nx[2]; wb3 = nx[3]; }
    f2 vA[8], vB[8];
    float wgtA, wgtB;

    // prologue: i = 0 (tree exposed once per pass)
    {
      mat8(&xr[Bbase][0], wa0, wa1, wa2, wa3, vA);
      float e = qexp(vA);
      float se = redsum32(e);
      float t = __builtin_amdgcn_rcpf(se + 1e-35f);
      float r2 = e * t;
      if (doStore) rowout[0] = r2;
      wgtA = r2 * a_sh[Bbase];
    }
    for (int pr = 0; pr < 8; ++pr) {
      const int iB = 2 * pr + 1, iC = iB + 1;
      {   // odd iteration iB: consume wb; prefetch iC into wa
        const float4* nx = wp + (size_t)iC * 128;
        float4 n0 = nx[0], n1 = nx[1], n2 = nx[2], n3 = nx[3];
        mat8(&xr[Bbase + iB][0], wb0, wb1, wb2, wb3, vB);
        wa0 = n0; wa1 = n1; wa2 = n2; wa3 = n3;
        float e = qexp(vB);
        float se = redsum32(e);
        accum(vA, wgtA);                    // fills the tree's stall shadow
        float t = __builtin_amdgcn_rcpf(se + 1e-35f);
        float r2 = e * t;
        if (doStore) rowout[(size_t)iB * 32] = r2;
        wgtB = r2 * a_sh[Bbase + iB];
      }
      {   // even iteration iC: consume wa; prefetch iC+1 into wb
        const float4* nx = wp + (size_t)(iC + 1) * 128;
        float4 n0 = nx[0], n1 = nx[1], n2 = nx[2], n3 = nx[3];
        mat8(&xr[Bbase + iC][0], wa0, wa1, wa2, wa3, vA);
        wb0 = n0; wb1 = n1; wb2 = n2; wb3 = n3;
        float e = qexp(vA);
        float se = redsum32(e);
        accum(vB, wgtB);
        float t = __builtin_amdgcn_rcpf(se + 1e-35f);
        float r2 = e * t;
        if (doStore) rowout[(size_t)iC * 32] = r2;
        wgtA = r2 * a_sh[Bbase + iC];
      }
    }
    // epilogue: i = 17 (wb prefetched by the last even step)
    {
      mat8(&xr[Bbase + 17][0], wb0, wb1, wb2, wb3, vB);
      float e = qexp(vB);
      float se = redsum32(e);
      accum(vA, wgtA);
      float t = __builtin_amdgcn_rcpf(se + 1e-35f);
      float r2 = e * t;
      if (doStore) rowout[(size_t)17 * 32] = r2;
      wgtB = r2 * a_sh[Bbase + 17];
      accum(vB, wgtB);
    }
    finalize();
  }

  // ---- outputs: row n = [mu (512) | a_out (32)], coalesced ----
  {
    int c2 = tid >> 4;
    int s = tid & 15;
    out[(size_t)n * 544 + tid] = mu_l[c2][s];
  }
  if (tid < 32) out[(size_t)n * 544 + 512 + tid] = aout_l[tid];
}

extern "C" void kernel_launch(void* const* d_in, const int* in_sizes, int n_in,
                              void* d_out, int out_size, void* d_ws, size_t ws_size,
                              hipStream_t stream) {
  const float* x  = (const float*)d_in[0];
  const float* w  = (const float*)d_in[1];
  const float* bu = (const float*)d_in[2];
  const float* ba = (const float*)d_in[3];
  float* out = (float*)d_out;
  convcaps_kernel<<<dim3(508), dim3(512), 0, stream>>>(x, w, bu, ba, out);
}